// Round 12
// baseline (3720.438 us; speedup 1.0000x reference)
//
#include <hip/hip_runtime.h>
#include <hip/hip_bf16.h>

typedef __hip_bfloat16 bf16;
typedef unsigned short ushortT;
typedef unsigned int uintT;
typedef unsigned long long u64;
typedef __attribute__((ext_vector_type(8))) short bf16x8;
typedef __attribute__((ext_vector_type(4))) float f32x4;

#define D 128
#define NLEV 5
#define TE 16
#define TN 16
#define GRID 768   // 3 blocks/CU x 256 CUs; LDS 48.2KB -> exactly 3/CU co-resident

// weight blob element offsets (bf16 elements), all stored transposed [C][K]
#define OFF_S1 0
#define OFF_S2 81920
#define OFF_F1 163840
#define OFF_F2 294912
#define OFF_NF1 360448
#define OFF_NF2 376832
#define OFF_GSH 393216
#define OFF_GFH 638976
#define OFF_GSL 884736
#define OFF_GFL 1130496
#define WT_TOTAL 1376256

__constant__ int TMAP[6] = { -1, 3, 1, 0, 4, 2 };
__constant__ int FMAP[6] = { -1, 2, -1, 0, 3, 1 };

__device__ int g_flag;

__device__ __forceinline__ float sigm(float x) { return 1.0f / (1.0f + __expf(-x)); }

__device__ __forceinline__ ushortT f2b(float v) {
    bf16 h = __float2bfloat16(v);
    return *reinterpret_cast<ushortT*>(&h);
}

__device__ __forceinline__ float ldx(int isb, const void* p, size_t i) {
    return isb ? __bfloat162float(((const bf16*)p)[i]) : ((const float*)p)[i];
}

// device-scope atomic store helpers (avoid L1 write-allocate staleness in persistent kernel)
__device__ __forceinline__ void st_u64(void* p, u64 v) {
    __hip_atomic_store((u64*)p, v, __ATOMIC_RELAXED, __HIP_MEMORY_SCOPE_AGENT);
}
__device__ __forceinline__ void st_u32(void* p, uintT v) {
    __hip_atomic_store((uintT*)p, v, __ATOMIC_RELAXED, __HIP_MEMORY_SCOPE_AGENT);
}

// ---- dtype sniffer ----
__global__ void detect_dtype(const void* hs_init) {
    int t = threadIdx.x;
    float x = __bfloat162float(((const bf16*)hs_init)[2 * t]);
    float ax = fabsf(x);
    bool sane = (x == 0.0f) || (ax > 1e-4f && ax < 64.0f);
    unsigned long long m = __ballot(sane);
    if (t == 0) g_flag = (__popcll(m) >= 32) ? 1 : 0;
}

// ========== bucketing (unchanged structure from R11) ==========
__global__ void count_bins(const int* __restrict__ dstA, const int* __restrict__ gate,
                           const int* __restrict__ lev, int E, int N,
                           int* __restrict__ ecnt, int* __restrict__ ncnt,
                           int* __restrict__ ndeg) {
    __shared__ int lc[40];
    int tid = threadIdx.x;
    if (tid < 40) lc[tid] = 0;
    __syncthreads();
    int i = blockIdx.x * blockDim.x + tid;
    if (i < E) {
        int d = dstA[i]; int l = lev[d];
        if (l >= 1 && l < NLEV) {
            atomicAdd(&lc[(l - 1) * 5 + TMAP[gate[d]]], 1);
            atomicAdd(&ndeg[d], 1);
        }
    }
    if (i < N) {
        int l = lev[i];
        if (l >= 1 && l < NLEV && gate[i] >= 1) atomicAdd(&lc[20 + (l - 1) * 5 + TMAP[gate[i]]], 1);
    }
    __syncthreads();
    if (tid < 20 && lc[tid]) atomicAdd(&ecnt[tid], lc[tid]);
    if (tid >= 20 && tid < 40 && lc[tid]) atomicAdd(&ncnt[tid - 20], lc[tid]);
}

__global__ void scan_offsets(const int* __restrict__ ecnt, const int* __restrict__ ncnt,
                             int* __restrict__ eoff, int* __restrict__ noff) {
    if (threadIdx.x == 0 && blockIdx.x == 0) {
        int o = 0;
        for (int b = 0; b < 20; ++b) { eoff[b] = o; o += ((ecnt[b] + TE - 1) / TE) * TE; }
        eoff[20] = o;
        o = 0;
        for (int b = 0; b < 20; ++b) { noff[b] = o; o += ((ncnt[b] + TN - 1) / TN) * TN; }
        noff[20] = o;
    }
}

__global__ void fill_bins(const int* __restrict__ gate, const int* __restrict__ lev, int N,
                          const int* __restrict__ noff, int* __restrict__ ncur,
                          int* __restrict__ nlist) {
    __shared__ int nc[20], nb[20];
    int tid = threadIdx.x;
    if (tid < 20) nc[tid] = 0;
    __syncthreads();
    int i = blockIdx.x * blockDim.x + tid;
    int bn = -1, rn = 0;
    if (i < N) {
        int l = lev[i];
        if (l >= 1 && l < NLEV && gate[i] >= 1) { bn = (l - 1) * 5 + TMAP[gate[i]]; rn = atomicAdd(&nc[bn], 1); }
    }
    __syncthreads();
    if (tid < 20) nb[tid] = nc[tid] ? atomicAdd(&ncur[tid], nc[tid]) : 0;
    __syncthreads();
    if (bn >= 0) nlist[noff[bn] + nb[bn] + rn] = i;
}

__global__ __launch_bounds__(256) void bucket_scan(
    const int* __restrict__ nlist, const int* __restrict__ noff,
    const int* __restrict__ ncnt, const int* __restrict__ eoff,
    const int* __restrict__ ndeg, int* __restrict__ nodeoff) {
    int b = blockIdx.x;
    int start = noff[b];
    int cnt = ncnt[b];
    int ebase = eoff[b];
    __shared__ int sc[256];
    int tid = threadIdx.x;
    int carry = 0;
    for (int chunk = 0; chunk < cnt; chunk += 256) {
        __syncthreads();
        int i = chunk + tid;
        int v = -1, dg = 0;
        if (i < cnt) { v = nlist[start + i]; dg = ndeg[v]; }
        sc[tid] = dg;
        __syncthreads();
        for (int off = 1; off < 256; off <<= 1) {
            int y = (tid >= off) ? sc[tid - off] : 0;
            __syncthreads();
            sc[tid] += y;
            __syncthreads();
        }
        if (v >= 0) nodeoff[v] = ebase + carry + (sc[tid] - dg);
        carry += sc[255];
    }
}

__global__ void fill_edges(const int* __restrict__ dstA, const int* __restrict__ lev,
                           int E, const int* __restrict__ nodeoff,
                           int* __restrict__ ecur_n, int* __restrict__ elist) {
    int i = blockIdx.x * blockDim.x + threadIdx.x;
    if (i >= E) return;
    int d = dstA[i];
    int l = lev[d];
    if (l >= 1 && l < NLEV) {
        int pos = nodeoff[d] + atomicAdd(&ecur_n[d], 1);
        elist[pos] = i;
    }
}

// ========== grid barrier (co-resident persistent grid) ==========
__device__ void gbar(int* cnt, int* gen) {
    __syncthreads();
    if (threadIdx.x == 0) {
        __threadfence();
        int g = __hip_atomic_load(gen, __ATOMIC_ACQUIRE, __HIP_MEMORY_SCOPE_AGENT);
        if (atomicAdd(cnt, 1) == (int)gridDim.x - 1) {
            __hip_atomic_store(cnt, 0, __ATOMIC_RELAXED, __HIP_MEMORY_SCOPE_AGENT);
            __hip_atomic_fetch_add(gen, 1, __ATOMIC_RELEASE, __HIP_MEMORY_SCOPE_AGENT);
        } else {
            while (__hip_atomic_load(gen, __ATOMIC_ACQUIRE, __HIP_MEMORY_SCOPE_AGENT) == g)
                __builtin_amdgcn_s_sleep(8);
        }
        __threadfence();
    }
    __syncthreads();
}

// ========== edge tile (MFMA, dst-grouped, LDS pre-reduced atomics) ==========
__device__ void edge_tile(
    int base, int isb, char* smem,
    const ushortT* __restrict__ hsb, const ushortT* __restrict__ hfb,
    const ushortT* __restrict__ wt,
    const void* bs1, const void* bs2, const void* bf1, const void* bf2,
    const void* bnf1, const void* bnf2,
    const int* __restrict__ dstA, const int* __restrict__ srcA,
    const int* __restrict__ gate, const int* __restrict__ elist,
    float* __restrict__ agg_s, float* __restrict__ agg_f) {
    int* se = (int*)smem;
    int* de = se + TE;
    bf16 (*hid)[16][136] = (bf16(*)[16][136])(smem + 128);
    float (*emsg)[16][128] = (float(*)[16][128])(smem + 128 + 8704);

    int tid = threadIdx.x;
    int wv = tid >> 6, pass = wv >> 1, hc = wv & 1, l = tid & 63;
    int lg = l >> 4, lr = l & 15;

    int c = gate[dstA[elist[base]]];
    int t = TMAP[c], fi = FMAP[c];

    if (tid < TE) {
        int e = elist[base + tid];
        se[tid] = (e < 0) ? -1 : srcA[e];
        de[tid] = (e < 0) ? -1 : dstA[e];
    }
    __syncthreads();

    int src = se[lr];

    int KS1; size_t wb1; int K1;
    if (pass == 0)      { KS1 = 4; wb1 = OFF_S1 + (size_t)t * 16384; K1 = 128; }
    else if (c == 2)    { KS1 = 4; wb1 = OFF_NF1; K1 = 128; }
    else                { KS1 = 8; wb1 = OFF_F1 + (size_t)fi * 32768; K1 = 256; }

    f32x4 a0 = {0.f,0.f,0.f,0.f}, a1 = a0, a2 = a0, a3 = a0;
    for (int ks = 0; ks < KS1; ++ks) {
        bf16x8 a = {0,0,0,0,0,0,0,0};
        if (src >= 0) {
            int kk = ks * 32 + lg * 8;
            const ushortT* ap;
            if (pass == 0)      ap = hsb + (size_t)src * D + kk;
            else if (c == 2)    ap = hfb + (size_t)src * D + kk;
            else                ap = (kk < 128) ? (hsb + (size_t)src * D + kk)
                                                : (hfb + (size_t)src * D + (kk - 128));
            a = *(const bf16x8*)ap;
        }
        int kb = ks * 32 + lg * 8;
        {
            bf16x8 b = *(const bf16x8*)&wt[wb1 + (size_t)(hc * 64 + 0 * 16 + lr) * K1 + kb];
            a0 = __builtin_amdgcn_mfma_f32_16x16x32_bf16(a, b, a0, 0, 0, 0);
        }
        {
            bf16x8 b = *(const bf16x8*)&wt[wb1 + (size_t)(hc * 64 + 1 * 16 + lr) * K1 + kb];
            a1 = __builtin_amdgcn_mfma_f32_16x16x32_bf16(a, b, a1, 0, 0, 0);
        }
        {
            bf16x8 b = *(const bf16x8*)&wt[wb1 + (size_t)(hc * 64 + 2 * 16 + lr) * K1 + kb];
            a2 = __builtin_amdgcn_mfma_f32_16x16x32_bf16(a, b, a2, 0, 0, 0);
        }
        {
            bf16x8 b = *(const bf16x8*)&wt[wb1 + (size_t)(hc * 64 + 3 * 16 + lr) * K1 + kb];
            a3 = __builtin_amdgcn_mfma_f32_16x16x32_bf16(a, b, a3, 0, 0, 0);
        }
    }

    const void* b1p = (pass == 0) ? bs1 : (c == 2 ? bnf1 : bf1);
    size_t b1o = (pass == 0) ? (size_t)t * D : (c == 2 ? 0 : (size_t)fi * D);
    {
        f32x4 av[4] = { a0, a1, a2, a3 };
#pragma unroll
        for (int ct = 0; ct < 4; ++ct) {
            int cc = hc * 64 + ct * 16 + lr;
            float bb = ldx(isb, b1p, b1o + cc);
#pragma unroll
            for (int r = 0; r < 4; ++r) {
                int m = lg * 4 + r;
                float v = fmaxf(av[ct][r] + bb, 0.f);
                hid[pass][m][cc] = __float2bfloat16(v);
            }
        }
    }
    __syncthreads();

    size_t wb2 = (pass == 0) ? (OFF_S2 + (size_t)t * 16384)
                             : (c == 2 ? (size_t)OFF_NF2 : (OFF_F2 + (size_t)fi * 16384));
    a0 = (f32x4){0.f,0.f,0.f,0.f}; a1 = a0; a2 = a0; a3 = a0;
#pragma unroll
    for (int ks = 0; ks < 4; ++ks) {
        bf16x8 a = *(const bf16x8*)&hid[pass][lr][ks * 32 + lg * 8];
        int kb = ks * 32 + lg * 8;
        {
            bf16x8 b = *(const bf16x8*)&wt[wb2 + (size_t)(hc * 64 + 0 * 16 + lr) * 128 + kb];
            a0 = __builtin_amdgcn_mfma_f32_16x16x32_bf16(a, b, a0, 0, 0, 0);
        }
        {
            bf16x8 b = *(const bf16x8*)&wt[wb2 + (size_t)(hc * 64 + 1 * 16 + lr) * 128 + kb];
            a1 = __builtin_amdgcn_mfma_f32_16x16x32_bf16(a, b, a1, 0, 0, 0);
        }
        {
            bf16x8 b = *(const bf16x8*)&wt[wb2 + (size_t)(hc * 64 + 2 * 16 + lr) * 128 + kb];
            a2 = __builtin_amdgcn_mfma_f32_16x16x32_bf16(a, b, a2, 0, 0, 0);
        }
        {
            bf16x8 b = *(const bf16x8*)&wt[wb2 + (size_t)(hc * 64 + 3 * 16 + lr) * 128 + kb];
            a3 = __builtin_amdgcn_mfma_f32_16x16x32_bf16(a, b, a3, 0, 0, 0);
        }
    }

    const void* b2p = (pass == 0) ? bs2 : (c == 2 ? bnf2 : bf2);
    size_t b2o = (pass == 0) ? (size_t)t * D : (c == 2 ? 0 : (size_t)fi * D);
    {
        f32x4 av[4] = { a0, a1, a2, a3 };
#pragma unroll
        for (int ct = 0; ct < 4; ++ct) {
            int cc = hc * 64 + ct * 16 + lr;
            float bb = ldx(isb, b2p, b2o + cc);
#pragma unroll
            for (int r = 0; r < 4; ++r) {
                int m = lg * 4 + r;
                emsg[pass][m][cc] = av[ct][r] + bb;
            }
        }
    }
    __syncthreads();

    float* aggp = pass ? agg_f : agg_s;
    int col = hc * 64 + l;
    float s = 0.f;
    for (int m = 0; m < TE; ++m) {
        int d = de[m];
        if (d < 0) break;
        s += emsg[pass][m][col];
        bool flush = (m == TE - 1) || (de[m + 1] != d);
        if (flush) {
            atomicAdd(&aggp[(size_t)d * D + col], s);
            s = 0.f;
        }
    }
    __syncthreads();   // protect se/de/emsg for next grid-stride iteration
}

// ========== node tile (4 waves; MFMA hi/lo; fused GRU epilogue) ==========
__device__ void node_tile(
    int base, int isb, char* smem,
    const float* __restrict__ agg_s, const float* __restrict__ agg_f,
    const ushortT* __restrict__ wt,
    const void* Gs_bih, const void* Gs_bhh, const void* Gf_bih, const void* Gf_bhh,
    float* __restrict__ hs, float* __restrict__ hf,
    ushortT* __restrict__ hsb, ushortT* __restrict__ hfb,
    const int* __restrict__ gate, const int* __restrict__ nlist) {
    float (*gi)[3][16][128] = (float(*)[3][16][128])smem;
    int tid = threadIdx.x;
    int w = tid >> 6, l = tid & 63;
    int lg = l >> 4, lr = l & 15;
    int p = w >> 1, cg = w & 1;
    int t = TMAP[gate[nlist[base]]];

    const float* agg = p ? agg_f : agg_s;
    size_t wbh = (p ? OFF_GFH : OFF_GSH) + (size_t)t * 49152;
    size_t wbl = (p ? OFF_GFL : OFF_GSL) + (size_t)t * 49152;

    int v = nlist[base + lr];

    f32x4 acc[12];
#pragma unroll
    for (int q = 0; q < 12; ++q) acc[q] = (f32x4){0.f, 0.f, 0.f, 0.f};

#pragma unroll
    for (int ks = 0; ks < 4; ++ks) {
        bf16x8 ahi = {0,0,0,0,0,0,0,0}, alo = ahi;
        if (v >= 0) {
            const float* ap = agg + (size_t)v * D + ks * 32 + lg * 8;
            float4 f0 = *(const float4*)ap;
            float4 f1 = *(const float4*)(ap + 4);
            float av[8] = { f0.x, f0.y, f0.z, f0.w, f1.x, f1.y, f1.z, f1.w };
#pragma unroll
            for (int j = 0; j < 8; ++j) {
                bf16 h = __float2bfloat16(av[j]);
                ahi[j] = (short)*reinterpret_cast<ushortT*>(&h);
                float r = av[j] - __bfloat162float(h);
                bf16 l2 = __float2bfloat16(r);
                alo[j] = (short)*reinterpret_cast<ushortT*>(&l2);
            }
        }
        int kb = ks * 32 + lg * 8;
#pragma unroll
        for (int q = 0; q < 12; ++q) {
            int col = (cg * 12 + q) * 16 + lr;
            bf16x8 bh = *(const bf16x8*)&wt[wbh + (size_t)col * 128 + kb];
            acc[q] = __builtin_amdgcn_mfma_f32_16x16x32_bf16(ahi, bh, acc[q], 0, 0, 0);
            acc[q] = __builtin_amdgcn_mfma_f32_16x16x32_bf16(alo, bh, acc[q], 0, 0, 0);
            if (!isb) {
                bf16x8 bl = *(const bf16x8*)&wt[wbl + (size_t)col * 128 + kb];
                acc[q] = __builtin_amdgcn_mfma_f32_16x16x32_bf16(ahi, bl, acc[q], 0, 0, 0);
            }
        }
    }

#pragma unroll
    for (int q = 0; q < 12; ++q) {
        int ct = cg * 12 + q;
        int g = ct >> 3, j = (ct & 7) * 16 + lr;
#pragma unroll
        for (int r = 0; r < 4; ++r) gi[p][g][lg * 4 + r][j] = acc[q][r];
    }
    __syncthreads();

    {
        int pp = tid >> 7, j = tid & 127;
        const void* bih = pp ? Gf_bih : Gs_bih;
        const void* bhh = pp ? Gf_bhh : Gs_bhh;
        float br = ldx(isb, bih, (size_t)t * 384 + j);
        float bz = ldx(isb, bih, (size_t)t * 384 + 128 + j);
        float bn = ldx(isb, bih, (size_t)t * 384 + 256 + j);
        float hr = ldx(isb, bhh, (size_t)t * 384 + j);
        float hz = ldx(isb, bhh, (size_t)t * 384 + 128 + j);
        float hn = ldx(isb, bhh, (size_t)t * 384 + 256 + j);
        float* ho = pp ? hf : hs;
        ushortT* hb = pp ? hfb : hsb;
#pragma unroll
        for (int r = 0; r < TN; ++r) {
            int vv = nlist[base + r];
            float out = 0.f;
            bool valid = (vv >= 0);
            if (valid) {
                float rr = sigm(gi[pp][0][r][j] + br + hr);
                float z = sigm(gi[pp][1][r][j] + bz + hz);
                float n = tanhf(gi[pp][2][r][j] + bn + rr * hn);
                out = (1.f - z) * n;
            }
            float nxt = __shfl_down(out, 1);
            if (valid && !(j & 1)) {
                u64 pk = ((u64)__float_as_uint(nxt) << 32) | (u64)__float_as_uint(out);
                st_u64(&ho[(size_t)vv * D + j], pk);
                uintT bp = (uintT)f2b(out) | ((uintT)f2b(nxt) << 16);
                st_u32(&hb[(size_t)vv * D + j], bp);
            }
        }
    }
    __syncthreads();   // protect gi for next grid-stride iteration
}

// ========== persistent fused kernel: P0 + 4 levels + writeout ==========
__global__ __launch_bounds__(256, 3) void fused_all(
    const void* hs_init,
    const void* Ws1, const void* bs1, const void* Ws2, const void* bs2,
    const void* Wf1, const void* bf1, const void* Wf2, const void* bf2,
    const void* Wnf1, const void* bnf1, const void* Wnf2, const void* bnf2,
    const void* Gs_wih, const void* Gs_bih, const void* Gs_bhh,
    const void* Gf_wih, const void* Gf_bih, const void* Gf_bhh,
    const int* dstA, const int* srcA, const int* gate,
    const int* eoff, const int* elist, const int* noff, const int* nlist,
    float* hs, float* hf, ushortT* hsb, ushortT* hfb,
    float* agg_s, float* agg_f, ushortT* wt,
    int* bar_cnt, int* bar_gen, void* out, int N) {
    __shared__ __align__(16) char smem[49280];
    int isb = g_flag;
    int ND = N * D;
    int gid = blockIdx.x * blockDim.x + threadIdx.x;
    int gsz = gridDim.x * blockDim.x;

    // ---- P0a: init states (atomic stores; no L1 pollution) ----
    for (int i = gid; i < ND / 2; i += gsz) {
        int v = (2 * i) / D, j = (2 * i) % D;
        float v0 = 0.f, v1 = 0.f;
        ushortT s0 = 0, s1 = 0;
        if (gate[v] == 0) {
            size_t idx = (size_t)v * D + j;
            if (isb) {
                s0 = ((const ushortT*)hs_init)[idx];
                s1 = ((const ushortT*)hs_init)[idx + 1];
                bf16 h0 = *reinterpret_cast<bf16*>(&s0);
                bf16 h1 = *reinterpret_cast<bf16*>(&s1);
                v0 = __bfloat162float(h0);
                v1 = __bfloat162float(h1);
            } else {
                v0 = ((const float*)hs_init)[idx];
                v1 = ((const float*)hs_init)[idx + 1];
                s0 = f2b(v0);
                s1 = f2b(v1);
            }
        }
        u64 pk = ((u64)__float_as_uint(v1) << 32) | (u64)__float_as_uint(v0);
        st_u64((u64*)hs + i, pk);
        st_u64((u64*)hf + i, 0ULL);
        st_u32((uintT*)hsb + i, (uintT)s0 | ((uintT)s1 << 16));
        st_u32((uintT*)hfb + i, 0u);
    }
    // ---- P0b: zero agg (agg_s, agg_f contiguous: 2*ND floats = ND u64) ----
    for (int i = gid; i < ND; i += gsz) st_u64((u64*)agg_s + i, 0ULL);
    // ---- P0c: weight prep (transpose + bf16 + GRU hi/lo) ----
    for (int i = gid; i < WT_TOTAL; i += gsz) {
        const void* src; int Kd, C, rem, mode = 0;
        if (i < OFF_S2)       { src = Ws1;    rem = i;           Kd = 128; C = 128; }
        else if (i < OFF_F1)  { src = Ws2;    rem = i - OFF_S2;  Kd = 128; C = 128; }
        else if (i < OFF_F2)  { src = Wf1;    rem = i - OFF_F1;  Kd = 256; C = 128; }
        else if (i < OFF_NF1) { src = Wf2;    rem = i - OFF_F2;  Kd = 128; C = 128; }
        else if (i < OFF_NF2) { src = Wnf1;   rem = i - OFF_NF1; Kd = 128; C = 128; }
        else if (i < OFF_GSH) { src = Wnf2;   rem = i - OFF_NF2; Kd = 128; C = 128; }
        else if (i < OFF_GFH) { src = Gs_wih; rem = i - OFF_GSH; Kd = 128; C = 384; mode = 1; }
        else if (i < OFF_GSL) { src = Gf_wih; rem = i - OFF_GFH; Kd = 128; C = 384; mode = 1; }
        else if (i < OFF_GFL) { src = Gs_wih; rem = i - OFF_GSL; Kd = 128; C = 384; mode = 2; }
        else                  { src = Gf_wih; rem = i - OFF_GFL; Kd = 128; C = 384; mode = 2; }
        int n = rem / (Kd * C);
        int r2 = rem % (Kd * C);
        int c = r2 / Kd;
        int k = r2 % Kd;
        size_t si = (size_t)n * Kd * C + (size_t)k * C + c;
        float v = ldx(isb, src, si);
        ushortT o;
        if (mode == 2) {
            bf16 h = __float2bfloat16(v);
            o = f2b(v - __bfloat162float(h));
        } else {
            o = f2b(v);
        }
        wt[i] = o;   // single write, never re-written: plain store safe
    }
    gbar(bar_cnt, bar_gen);

    // ---- level loop ----
    for (int level = 1; level < NLEV; ++level) {
        int lo = eoff[(level - 1) * 5], hiE = eoff[(level - 1) * 5 + 5];
        int nt = (hiE - lo) / TE;
        for (int ti = blockIdx.x; ti < nt; ti += gridDim.x)
            edge_tile(lo + ti * TE, isb, smem, hsb, hfb, wt,
                      bs1, bs2, bf1, bf2, bnf1, bnf2,
                      dstA, srcA, gate, elist, agg_s, agg_f);
        gbar(bar_cnt, bar_gen);
        int nlo = noff[(level - 1) * 5], nhiN = noff[(level - 1) * 5 + 5];
        int nn = (nhiN - nlo) / TN;
        for (int ti = blockIdx.x; ti < nn; ti += gridDim.x)
            node_tile(nlo + ti * TN, isb, smem, agg_s, agg_f, wt,
                      Gs_bih, Gs_bhh, Gf_bih, Gf_bhh,
                      hs, hf, hsb, hfb, gate, nlist);
        gbar(bar_cnt, bar_gen);
    }

    // ---- writeout (first read of hs/hf: coherent) ----
    for (int i = gid; i < ND; i += gsz) {
        if (isb) {
            ((ushortT*)out)[i] = f2b(hs[i]);
            ((ushortT*)out)[ND + i] = f2b(hf[i]);
        } else {
            ((float*)out)[i] = hs[i];
            ((float*)out)[ND + i] = hf[i];
        }
    }
}

extern "C" void kernel_launch(void* const* d_in, const int* in_sizes, int n_in,
                              void* d_out, int out_size, void* d_ws, size_t ws_size,
                              hipStream_t stream) {
    const void* hs_init = d_in[0];
    const void* Ws1 = d_in[1];
    const void* bs1 = d_in[2];
    const void* Ws2 = d_in[3];
    const void* bs2 = d_in[4];
    const void* Wf1 = d_in[5];
    const void* bf1 = d_in[6];
    const void* Wf2 = d_in[7];
    const void* bf2 = d_in[8];
    const void* Wnf1 = d_in[9];
    const void* bnf1 = d_in[10];
    const void* Wnf2 = d_in[11];
    const void* bnf2 = d_in[12];
    const void* Gs_wih = d_in[13];
    const void* Gs_bih = d_in[15];
    const void* Gs_bhh = d_in[16];
    const void* Gf_wih = d_in[17];
    const void* Gf_bih = d_in[19];
    const void* Gf_bhh = d_in[20];
    const int* edge_index = (const int*)d_in[21];
    const int* gate = (const int*)d_in[22];
    const int* lev = (const int*)d_in[23];

    int E = in_sizes[21] / 2;
    int N = in_sizes[22];
    int ND = N * D;

    float* hs = (float*)d_ws;
    float* hf = hs + ND;
    float* agg_s = hf + ND;
    float* agg_f = agg_s + ND;
    ushortT* hsb = (ushortT*)(agg_f + ND);
    ushortT* hfb = hsb + ND;
    ushortT* wt = hfb + ND;
    int* meta = (int*)(wt + WT_TOTAL);
    int* ecnt = meta;            // 20
    int* ncnt = ecnt + 20;       // 20
    int* ncur = ncnt + 20;       // 20
    int* eoff = ncur + 20;       // 21
    int* noff = eoff + 21;       // 21
    int* bar_cnt = meta + 102;
    int* bar_gen = meta + 103;
    int* ndeg = meta + 128;      // N
    int* ecur_n = ndeg + N;      // N
    int* nodeoff = ecur_n + N;   // N
    int* elist = nodeoff + N;    // E + 20*TE
    int* nlist = elist + (E + 20 * TE);  // N + 20*TN

    const int* srcA = edge_index;
    const int* dstA = edge_index + E;

    detect_dtype<<<1, 64, 0, stream>>>(hs_init);
    hipMemsetAsync(meta, 0, (size_t)(128 + 2 * N) * sizeof(int), stream);
    hipMemsetAsync(elist, 0xFF, (size_t)(E + 20 * TE + N + 20 * TN) * sizeof(int), stream);

    int mx = (E > N) ? E : N;
    count_bins<<<(mx + 255) / 256, 256, 0, stream>>>(dstA, gate, lev, E, N, ecnt, ncnt, ndeg);
    scan_offsets<<<1, 64, 0, stream>>>(ecnt, ncnt, eoff, noff);
    fill_bins<<<(N + 255) / 256, 256, 0, stream>>>(gate, lev, N, noff, ncur, nlist);
    bucket_scan<<<20, 256, 0, stream>>>(nlist, noff, ncnt, eoff, ndeg, nodeoff);
    fill_edges<<<(E + 255) / 256, 256, 0, stream>>>(dstA, lev, E, nodeoff, ecur_n, elist);

    fused_all<<<GRID, 256, 0, stream>>>(
        hs_init, Ws1, bs1, Ws2, bs2, Wf1, bf1, Wf2, bf2,
        Wnf1, bnf1, Wnf2, bnf2,
        Gs_wih, Gs_bih, Gs_bhh, Gf_wih, Gf_bih, Gf_bhh,
        dstA, srcA, gate, eoff, elist, noff, nlist,
        hs, hf, hsb, hfb, agg_s, agg_f, wt,
        bar_cnt, bar_gen, d_out, N);
}

// Round 13
// 256.598 us; speedup vs baseline: 14.4991x; 14.4991x over previous
//
#include <hip/hip_runtime.h>
#include <hip/hip_bf16.h>

typedef __hip_bfloat16 bf16;
typedef unsigned short ushortT;
typedef __attribute__((ext_vector_type(8))) short bf16x8;
typedef __attribute__((ext_vector_type(4))) float f32x4;

#define D 128
#define NLEV 5
#define TE 16  // edges per tile (MFMA M=16)
#define TN 16  // nodes per tile

// weight blob element offsets (bf16 elements), all stored transposed [C][K]
#define OFF_S1 0          // [5][128][128]
#define OFF_S2 81920      // [5][128][128]
#define OFF_F1 163840     // [4][128][256]
#define OFF_F2 294912     // [4][128][128]
#define OFF_NF1 360448    // [128][128]
#define OFF_NF2 376832    // [128][128]
#define OFF_GSH 393216    // [5][384][128] Gs_wih hi
#define OFF_GFH 638976    // [5][384][128] Gf_wih hi
#define OFF_GSL 884736    // [5][384][128] Gs_wih lo
#define OFF_GFL 1130496   // [5][384][128] Gf_wih lo
#define WT_TOTAL 1376256

// gate code -> t (enumerate index in CODES=[3,2,5,1,4]); index 0 unused
__constant__ int TMAP[6] = { -1, 3, 1, 0, 4, 2 };
// gate code -> func-aggregator index (FIDX={3:0,5:1,1:2,4:3}); codes 0,2 unused
__constant__ int FMAP[6] = { -1, 2, -1, 0, 3, 1 };

// dtype flag: 1 = float tensors stored as bf16, 0 = stored as float32
__device__ int g_flag;

__device__ __forceinline__ float sigm(float x) { return 1.0f / (1.0f + __expf(-x)); }

__device__ __forceinline__ ushortT f2b(float v) {
    bf16 h = __float2bfloat16(v);
    return *reinterpret_cast<ushortT*>(&h);
}

template <int ISB>
__device__ __forceinline__ float ld(const void* p, size_t i) {
    if (ISB) return __bfloat162float(((const bf16*)p)[i]);
    return ((const float*)p)[i];
}

// ---- dtype sniffer ----
__global__ void detect_dtype(const void* hs_init) {
    int t = threadIdx.x;
    float x = __bfloat162float(((const bf16*)hs_init)[2 * t]);
    float ax = fabsf(x);
    bool sane = (x == 0.0f) || (ax > 1e-4f && ax < 64.0f);
    unsigned long long m = __ballot(sane);
    if (t == 0) g_flag = (__popcll(m) >= 32) ? 1 : 0;
}

// ---- init: bf16 state mirrors + PI/zero rows of the OUTPUT directly ----
// (each non-PI node is written to out exactly once, by node_fused at its level)
__global__ void init_state(const void* __restrict__ hs_init,
                           const int* __restrict__ gate,
                           ushortT* __restrict__ hsb, ushortT* __restrict__ hfb,
                           void* __restrict__ out, int ND) {
    int v = blockIdx.x;
    int j = threadIdx.x;
    size_t idx = (size_t)v * D + j;
    bool pi = (gate[v] == 0);
    if (g_flag) {
        ushortT bval = pi ? ((const ushortT*)hs_init)[idx] : 0;  // exact bf16 copy
        hsb[idx] = bval; hfb[idx] = 0;
        ((ushortT*)out)[idx] = bval;
        ((ushortT*)out)[ND + idx] = 0;
    } else {
        float val = pi ? ((const float*)hs_init)[idx] : 0.f;
        hsb[idx] = f2b(val); hfb[idx] = 0;
        ((float*)out)[idx] = val;
        ((float*)out)[ND + idx] = 0.f;
    }
}

// ---- fused weight prep: all transposes + bf16 convert + GRU hi/lo split ----
__global__ void prep_weights(const void* __restrict__ Ws1, const void* __restrict__ Ws2,
                             const void* __restrict__ Wf1, const void* __restrict__ Wf2,
                             const void* __restrict__ Wnf1, const void* __restrict__ Wnf2,
                             const void* __restrict__ Gs, const void* __restrict__ Gf,
                             ushortT* __restrict__ wt) {
    int i = blockIdx.x * blockDim.x + threadIdx.x;
    if (i >= WT_TOTAL) return;
    const void* src; int Kd, C, rem, mode = 0;  // mode 0: plain, 1: hi, 2: lo
    if (i < OFF_S2)       { src = Ws1;  rem = i;           Kd = 128; C = 128; }
    else if (i < OFF_F1)  { src = Ws2;  rem = i - OFF_S2;  Kd = 128; C = 128; }
    else if (i < OFF_F2)  { src = Wf1;  rem = i - OFF_F1;  Kd = 256; C = 128; }
    else if (i < OFF_NF1) { src = Wf2;  rem = i - OFF_F2;  Kd = 128; C = 128; }
    else if (i < OFF_NF2) { src = Wnf1; rem = i - OFF_NF1; Kd = 128; C = 128; }
    else if (i < OFF_GSH) { src = Wnf2; rem = i - OFF_NF2; Kd = 128; C = 128; }
    else if (i < OFF_GFH) { src = Gs;   rem = i - OFF_GSH; Kd = 128; C = 384; mode = 1; }
    else if (i < OFF_GSL) { src = Gf;   rem = i - OFF_GFH; Kd = 128; C = 384; mode = 1; }
    else if (i < OFF_GFL) { src = Gs;   rem = i - OFF_GSL; Kd = 128; C = 384; mode = 2; }
    else                  { src = Gf;   rem = i - OFF_GFL; Kd = 128; C = 384; mode = 2; }
    int n = rem / (Kd * C);
    int r2 = rem % (Kd * C);
    int c = r2 / Kd;
    int k = r2 % Kd;
    size_t si = (size_t)n * Kd * C + (size_t)k * C + c;
    float v = g_flag ? ld<1>(src, si) : ld<0>(src, si);
    ushortT out;
    if (mode == 2) {
        bf16 h = __float2bfloat16(v);
        out = f2b(v - __bfloat162float(h));   // lo residue (0 when src is bf16)
    } else {
        out = f2b(v);
    }
    wt[i] = out;
}

// ========== bucketing: (level-1)*5 + t, levels 1..4; edges dst-grouped ==========
__global__ void count_bins(const int* __restrict__ dstA, const int* __restrict__ gate,
                           const int* __restrict__ lev, int E, int N,
                           int* __restrict__ ecnt, int* __restrict__ ncnt,
                           int* __restrict__ ndeg) {
    __shared__ int lc[40];
    int tid = threadIdx.x;
    if (tid < 40) lc[tid] = 0;
    __syncthreads();
    int i = blockIdx.x * blockDim.x + tid;
    if (i < E) {
        int d = dstA[i]; int l = lev[d];
        if (l >= 1 && l < NLEV) {
            atomicAdd(&lc[(l - 1) * 5 + TMAP[gate[d]]], 1);
            atomicAdd(&ndeg[d], 1);
        }
    }
    if (i < N) {
        int l = lev[i];
        if (l >= 1 && l < NLEV && gate[i] >= 1) atomicAdd(&lc[20 + (l - 1) * 5 + TMAP[gate[i]]], 1);
    }
    __syncthreads();
    if (tid < 20 && lc[tid]) atomicAdd(&ecnt[tid], lc[tid]);
    if (tid >= 20 && tid < 40 && lc[tid]) atomicAdd(&ncnt[tid - 20], lc[tid]);
}

__global__ void scan_offsets(const int* __restrict__ ecnt, const int* __restrict__ ncnt,
                             int* __restrict__ eoff, int* __restrict__ noff) {
    if (threadIdx.x == 0 && blockIdx.x == 0) {
        int o = 0;
        for (int b = 0; b < 20; ++b) { eoff[b] = o; o += ((ecnt[b] + TE - 1) / TE) * TE; }
        eoff[20] = o;
        o = 0;
        for (int b = 0; b < 20; ++b) { noff[b] = o; o += ((ncnt[b] + TN - 1) / TN) * TN; }
        noff[20] = o;
    }
}

// nodes -> nlist (bucketed, padded with -1)
__global__ void fill_bins(const int* __restrict__ gate, const int* __restrict__ lev, int N,
                          const int* __restrict__ noff, int* __restrict__ ncur,
                          int* __restrict__ nlist) {
    __shared__ int nc[20], nb[20];
    int tid = threadIdx.x;
    if (tid < 20) nc[tid] = 0;
    __syncthreads();
    int i = blockIdx.x * blockDim.x + tid;
    int bn = -1, rn = 0;
    if (i < N) {
        int l = lev[i];
        if (l >= 1 && l < NLEV && gate[i] >= 1) { bn = (l - 1) * 5 + TMAP[gate[i]]; rn = atomicAdd(&nc[bn], 1); }
    }
    __syncthreads();
    if (tid < 20) nb[tid] = nc[tid] ? atomicAdd(&ncur[tid], nc[tid]) : 0;
    __syncthreads();
    if (bn >= 0) nlist[noff[bn] + nb[bn] + rn] = i;
}

// per-bucket prefix-scan of node degrees -> nodeoff[v] (edge start within elist)
__global__ __launch_bounds__(256) void bucket_scan(
    const int* __restrict__ nlist, const int* __restrict__ noff,
    const int* __restrict__ ncnt, const int* __restrict__ eoff,
    const int* __restrict__ ndeg, int* __restrict__ nodeoff) {
    int b = blockIdx.x;  // 0..19
    int start = noff[b];
    int cnt = ncnt[b];
    int ebase = eoff[b];
    __shared__ int sc[256];
    int tid = threadIdx.x;
    int carry = 0;
    for (int chunk = 0; chunk < cnt; chunk += 256) {
        __syncthreads();
        int i = chunk + tid;
        int v = -1, dg = 0;
        if (i < cnt) { v = nlist[start + i]; dg = ndeg[v]; }
        sc[tid] = dg;
        __syncthreads();
        for (int off = 1; off < 256; off <<= 1) {
            int y = (tid >= off) ? sc[tid - off] : 0;
            __syncthreads();
            sc[tid] += y;
            __syncthreads();
        }
        if (v >= 0) nodeoff[v] = ebase + carry + (sc[tid] - dg);
        carry += sc[255];
    }
}

// edges -> elist, dst-contiguous
__global__ void fill_edges(const int* __restrict__ dstA, const int* __restrict__ lev,
                           int E, const int* __restrict__ nodeoff,
                           int* __restrict__ ecur_n, int* __restrict__ elist) {
    int i = blockIdx.x * blockDim.x + threadIdx.x;
    if (i >= E) return;
    int d = dstA[i];
    int l = lev[d];
    if (l >= 1 && l < NLEV) {
        int pos = nodeoff[d] + atomicAdd(&ecur_n[d], 1);
        elist[pos] = i;
    }
}

// ================= MFMA edge pass (dst-grouped tiles; LDS pre-reduced atomics) =================
// 4 waves/block: (pass in {struct, func}) x (col-half hc).
// A-frag (16x16x32 bf16): lane l supplies A[l&15][(l>>4)*8 + j]
// B-frag: lane l supplies B[(l>>4)*8 + j][l&15]  -> contiguous in W^T[c][k]
// D: lane l holds out[(l>>4)*4 + reg][l&15] (m89-verified mapping)
__global__ __launch_bounds__(256) void edge_mfma(
    const ushortT* __restrict__ hsb, const ushortT* __restrict__ hfb,
    const ushortT* __restrict__ wt,
    const void* __restrict__ bs1, const void* __restrict__ bs2,
    const void* __restrict__ bf1, const void* __restrict__ bf2,
    const void* __restrict__ bnf1, const void* __restrict__ bnf2,
    const int* __restrict__ dstA, const int* __restrict__ srcA,
    const int* __restrict__ gate,
    const int* __restrict__ eoff, const int* __restrict__ elist,
    float* __restrict__ agg_s, float* __restrict__ agg_f, int level) {
    int lo = eoff[(level - 1) * 5];
    int hi = eoff[(level - 1) * 5 + 5];
    int base = lo + blockIdx.x * TE;
    if (base >= hi) return;

    __shared__ int se[TE], de[TE];
    __shared__ bf16 hid[2][16][136];      // 272B rows: 16B-aligned
    __shared__ float emsg[2][16][128];    // per-edge messages (+bias) for pre-reduction

    int tid = threadIdx.x;
    int wv = tid >> 6, pass = wv >> 1, hc = wv & 1, l = tid & 63;
    int lg = l >> 4, lr = l & 15;
    int isb = g_flag;

    int c = gate[dstA[elist[base]]];   // uniform over tile (buckets padded)
    int t = TMAP[c], fi = FMAP[c];

    if (tid < TE) {
        int e = elist[base + tid];
        se[tid] = (e < 0) ? -1 : srcA[e];
        de[tid] = (e < 0) ? -1 : dstA[e];
    }
    __syncthreads();

    int src = se[lr];   // A-operand row owned by this lane

    // ---- layer 1 ----
    int KS1; size_t wb1; int K1;
    if (pass == 0)      { KS1 = 4; wb1 = OFF_S1 + (size_t)t * 16384; K1 = 128; }
    else if (c == 2)    { KS1 = 4; wb1 = OFF_NF1; K1 = 128; }
    else                { KS1 = 8; wb1 = OFF_F1 + (size_t)fi * 32768; K1 = 256; }

    f32x4 a0 = {0.f,0.f,0.f,0.f}, a1 = a0, a2 = a0, a3 = a0;
    for (int ks = 0; ks < KS1; ++ks) {
        bf16x8 a = {0,0,0,0,0,0,0,0};
        if (src >= 0) {
            int kk = ks * 32 + lg * 8;
            const ushortT* ap;
            if (pass == 0)      ap = hsb + (size_t)src * D + kk;
            else if (c == 2)    ap = hfb + (size_t)src * D + kk;
            else                ap = (kk < 128) ? (hsb + (size_t)src * D + kk)
                                                : (hfb + (size_t)src * D + (kk - 128));
            a = *(const bf16x8*)ap;
        }
        int kb = ks * 32 + lg * 8;
        {
            bf16x8 b = *(const bf16x8*)&wt[wb1 + (size_t)(hc * 64 + 0 * 16 + lr) * K1 + kb];
            a0 = __builtin_amdgcn_mfma_f32_16x16x32_bf16(a, b, a0, 0, 0, 0);
        }
        {
            bf16x8 b = *(const bf16x8*)&wt[wb1 + (size_t)(hc * 64 + 1 * 16 + lr) * K1 + kb];
            a1 = __builtin_amdgcn_mfma_f32_16x16x32_bf16(a, b, a1, 0, 0, 0);
        }
        {
            bf16x8 b = *(const bf16x8*)&wt[wb1 + (size_t)(hc * 64 + 2 * 16 + lr) * K1 + kb];
            a2 = __builtin_amdgcn_mfma_f32_16x16x32_bf16(a, b, a2, 0, 0, 0);
        }
        {
            bf16x8 b = *(const bf16x8*)&wt[wb1 + (size_t)(hc * 64 + 3 * 16 + lr) * K1 + kb];
            a3 = __builtin_amdgcn_mfma_f32_16x16x32_bf16(a, b, a3, 0, 0, 0);
        }
    }

    // bias + relu -> bf16 hidden in LDS
    const void* b1p = (pass == 0) ? bs1 : (c == 2 ? bnf1 : bf1);
    size_t b1o = (pass == 0) ? (size_t)t * D : (c == 2 ? 0 : (size_t)fi * D);
    {
        f32x4 av[4] = { a0, a1, a2, a3 };
#pragma unroll
        for (int ct = 0; ct < 4; ++ct) {
            int cc = hc * 64 + ct * 16 + lr;
            float bb = isb ? ld<1>(b1p, b1o + cc) : ld<0>(b1p, b1o + cc);
#pragma unroll
            for (int r = 0; r < 4; ++r) {
                int m = lg * 4 + r;
                float v = fmaxf(av[ct][r] + bb, 0.f);
                hid[pass][m][cc] = __float2bfloat16(v);
            }
        }
    }
    __syncthreads();

    // ---- layer 2 (K=128 over hidden) ----
    size_t wb2 = (pass == 0) ? (OFF_S2 + (size_t)t * 16384)
                             : (c == 2 ? (size_t)OFF_NF2 : (OFF_F2 + (size_t)fi * 16384));
    a0 = (f32x4){0.f,0.f,0.f,0.f}; a1 = a0; a2 = a0; a3 = a0;
#pragma unroll
    for (int ks = 0; ks < 4; ++ks) {
        bf16x8 a = *(const bf16x8*)&hid[pass][lr][ks * 32 + lg * 8];
        int kb = ks * 32 + lg * 8;
        {
            bf16x8 b = *(const bf16x8*)&wt[wb2 + (size_t)(hc * 64 + 0 * 16 + lr) * 128 + kb];
            a0 = __builtin_amdgcn_mfma_f32_16x16x32_bf16(a, b, a0, 0, 0, 0);
        }
        {
            bf16x8 b = *(const bf16x8*)&wt[wb2 + (size_t)(hc * 64 + 1 * 16 + lr) * 128 + kb];
            a1 = __builtin_amdgcn_mfma_f32_16x16x32_bf16(a, b, a1, 0, 0, 0);
        }
        {
            bf16x8 b = *(const bf16x8*)&wt[wb2 + (size_t)(hc * 64 + 2 * 16 + lr) * 128 + kb];
            a2 = __builtin_amdgcn_mfma_f32_16x16x32_bf16(a, b, a2, 0, 0, 0);
        }
        {
            bf16x8 b = *(const bf16x8*)&wt[wb2 + (size_t)(hc * 64 + 3 * 16 + lr) * 128 + kb];
            a3 = __builtin_amdgcn_mfma_f32_16x16x32_bf16(a, b, a3, 0, 0, 0);
        }
    }

    // per-edge bias folded in, stash to LDS for same-dst pre-reduction
    const void* b2p = (pass == 0) ? bs2 : (c == 2 ? bnf2 : bf2);
    size_t b2o = (pass == 0) ? (size_t)t * D : (c == 2 ? 0 : (size_t)fi * D);
    {
        f32x4 av[4] = { a0, a1, a2, a3 };
#pragma unroll
        for (int ct = 0; ct < 4; ++ct) {
            int cc = hc * 64 + ct * 16 + lr;
            float bb = isb ? ld<1>(b2p, b2o + cc) : ld<0>(b2p, b2o + cc);
#pragma unroll
            for (int r = 0; r < 4; ++r) {
                int m = lg * 4 + r;
                emsg[pass][m][cc] = av[ct][r] + bb;
            }
        }
    }
    __syncthreads();

    // run-detect on de[] (dst-grouped): one atomic per distinct dst per col
    float* aggp = pass ? agg_f : agg_s;
    int col = hc * 64 + l;
    float s = 0.f;
    for (int m = 0; m < TE; ++m) {
        int d = de[m];
        if (d < 0) break;                 // padding is contiguous at tile end
        s += emsg[pass][m][col];
        bool flush = (m == TE - 1) || (de[m + 1] != d);
        if (flush) {
            atomicAdd(&aggp[(size_t)d * D + col], s);
            s = 0.f;
        }
    }
}

// ===== fused node GRU: MFMA gi (hi/lo compensated) -> LDS -> nonlinearity =====
// 12 waves: wave w -> p = w/6, colgroup cg = w%6 (4 col-tiles of 16 each).
// Epilogue writes the FINAL output row for each node directly (one level per node).
template <int ISB>
__device__ void node_fused_body(
    const float* __restrict__ agg_s, const float* __restrict__ agg_f,
    const ushortT* __restrict__ wt,
    const void* __restrict__ Gs_bih, const void* __restrict__ Gs_bhh,
    const void* __restrict__ Gf_bih, const void* __restrict__ Gf_bhh,
    ushortT* __restrict__ hsb, ushortT* __restrict__ hfb,
    void* __restrict__ out, int ND,
    const int* __restrict__ gate,
    const int* __restrict__ noff, const int* __restrict__ nlist,
    int level, float (*gi)[3][16][128]) {
    int lo = noff[(level - 1) * 5];
    int hi = noff[(level - 1) * 5 + 5];
    int base = lo + blockIdx.x * TN;
    if (base >= hi) return;
    int tid = threadIdx.x;
    int w = tid >> 6, l = tid & 63;
    int lg = l >> 4, lr = l & 15;
    int p = w / 6, cg = w % 6;
    int t = TMAP[gate[nlist[base]]];

    const float* agg = p ? agg_f : agg_s;
    size_t wbh = (p ? OFF_GFH : OFF_GSH) + (size_t)t * 49152;
    size_t wbl = (p ? OFF_GFL : OFF_GSL) + (size_t)t * 49152;

    int v = nlist[base + lr];   // A-operand row owned by this lane

    f32x4 acc[4];
#pragma unroll
    for (int q = 0; q < 4; ++q) acc[q] = (f32x4){0.f, 0.f, 0.f, 0.f};

    for (int ks = 0; ks < 4; ++ks) {
        bf16x8 ahi = {0,0,0,0,0,0,0,0}, alo = ahi;
        if (v >= 0) {
            const float* ap = agg + (size_t)v * D + ks * 32 + lg * 8;
            float4 f0 = *(const float4*)ap;
            float4 f1 = *(const float4*)(ap + 4);
            float av[8] = { f0.x, f0.y, f0.z, f0.w, f1.x, f1.y, f1.z, f1.w };
#pragma unroll
            for (int j = 0; j < 8; ++j) {
                bf16 h = __float2bfloat16(av[j]);
                ahi[j] = (short)*reinterpret_cast<ushortT*>(&h);
                float r = av[j] - __bfloat162float(h);
                bf16 l2 = __float2bfloat16(r);
                alo[j] = (short)*reinterpret_cast<ushortT*>(&l2);
            }
        }
        int kb = ks * 32 + lg * 8;
#pragma unroll
        for (int q = 0; q < 4; ++q) {
            int col = (cg * 4 + q) * 16 + lr;
            bf16x8 bh = *(const bf16x8*)&wt[wbh + (size_t)col * 128 + kb];
            acc[q] = __builtin_amdgcn_mfma_f32_16x16x32_bf16(ahi, bh, acc[q], 0, 0, 0);
            acc[q] = __builtin_amdgcn_mfma_f32_16x16x32_bf16(alo, bh, acc[q], 0, 0, 0);
            if (!ISB) {   // f32 weights: add hi*lo correction (lo=0 when src bf16)
                bf16x8 bl = *(const bf16x8*)&wt[wbl + (size_t)col * 128 + kb];
                acc[q] = __builtin_amdgcn_mfma_f32_16x16x32_bf16(ahi, bl, acc[q], 0, 0, 0);
            }
        }
    }

#pragma unroll
    for (int q = 0; q < 4; ++q) {
        int ct = cg * 4 + q;
        int g = ct >> 3, j = (ct & 7) * 16 + lr;
#pragma unroll
        for (int r = 0; r < 4; ++r) gi[p][g][lg * 4 + r][j] = acc[q][r];
    }
    __syncthreads();

    if (tid < 256) {
        int pp = tid >> 7, j = tid & 127;
        const void* bih = pp ? Gf_bih : Gs_bih;
        const void* bhh = pp ? Gf_bhh : Gs_bhh;
        float br = ld<ISB>(bih, (size_t)t * 384 + j);
        float bz = ld<ISB>(bih, (size_t)t * 384 + 128 + j);
        float bn = ld<ISB>(bih, (size_t)t * 384 + 256 + j);
        float hr = ld<ISB>(bhh, (size_t)t * 384 + j);
        float hz = ld<ISB>(bhh, (size_t)t * 384 + 128 + j);
        float hn = ld<ISB>(bhh, (size_t)t * 384 + 256 + j);
        ushortT* hb = pp ? hfb : hsb;
#pragma unroll
        for (int r = 0; r < TN; ++r) {
            int vv = nlist[base + r];
            if (vv < 0) continue;
            float rr = sigm(gi[pp][0][r][j] + br + hr);
            float z = sigm(gi[pp][1][r][j] + bz + hz);
            float n = tanhf(gi[pp][2][r][j] + bn + rr * hn);
            float outv = (1.f - z) * n;
            size_t oidx = (size_t)pp * ND + (size_t)vv * D + j;
            if (ISB) ((ushortT*)out)[oidx] = f2b(outv);
            else     ((float*)out)[oidx] = outv;
            hb[(size_t)vv * D + j] = f2b(outv);
        }
    }
}

__global__ __launch_bounds__(768) void node_fused(
    const float* agg_s, const float* agg_f, const ushortT* wt,
    const void* Gs_bih, const void* Gs_bhh,
    const void* Gf_bih, const void* Gf_bhh,
    ushortT* hsb, ushortT* hfb, void* out, int ND,
    const int* gate, const int* noff, const int* nlist, int level) {
    __shared__ float gi[2][3][16][128];
    if (g_flag)
        node_fused_body<1>(agg_s, agg_f, wt, Gs_bih, Gs_bhh, Gf_bih, Gf_bhh,
                           hsb, hfb, out, ND, gate, noff, nlist, level, gi);
    else
        node_fused_body<0>(agg_s, agg_f, wt, Gs_bih, Gs_bhh, Gf_bih, Gf_bhh,
                           hsb, hfb, out, ND, gate, noff, nlist, level, gi);
}

extern "C" void kernel_launch(void* const* d_in, const int* in_sizes, int n_in,
                              void* d_out, int out_size, void* d_ws, size_t ws_size,
                              hipStream_t stream) {
    const void* hs_init = d_in[0];
    const void* Ws1 = d_in[1];
    const void* bs1 = d_in[2];
    const void* Ws2 = d_in[3];
    const void* bs2 = d_in[4];
    const void* Wf1 = d_in[5];
    const void* bf1 = d_in[6];
    const void* Wf2 = d_in[7];
    const void* bf2 = d_in[8];
    const void* Wnf1 = d_in[9];
    const void* bnf1 = d_in[10];
    const void* Wnf2 = d_in[11];
    const void* bnf2 = d_in[12];
    const void* Gs_wih = d_in[13];
    const void* Gs_bih = d_in[15];
    const void* Gs_bhh = d_in[16];
    const void* Gf_wih = d_in[17];
    const void* Gf_bih = d_in[19];
    const void* Gf_bhh = d_in[20];
    const int* edge_index = (const int*)d_in[21];
    const int* gate = (const int*)d_in[22];
    const int* lev = (const int*)d_in[23];

    int E = in_sizes[21] / 2;
    int N = in_sizes[22];
    int ND = N * D;
    int cap = ((N / NLEV + 5 * TN + 64) + TN - 1) / TN * TN;

    float* agg_s = (float*)d_ws;
    float* agg_f = agg_s + ND;
    ushortT* hsb = (ushortT*)(agg_f + ND);           // ND ushorts
    ushortT* hfb = hsb + ND;
    ushortT* wt = hfb + ND;                          // WT_TOTAL ushorts
    int* meta = (int*)(wt + WT_TOTAL);
    int* ecnt = meta;            // 20
    int* ncnt = ecnt + 20;       // 20
    int* ncur = ncnt + 20;       // 20
    int* eoff = ncur + 20;       // 21
    int* noff = eoff + 21;       // 21  (meta total 102; pad to 128)
    int* ndeg = meta + 128;      // N
    int* ecur_n = ndeg + N;      // N
    int* nodeoff = ecur_n + N;   // N
    int* elist = nodeoff + N;    // E + 20*TE
    int* nlist = elist + (E + 20 * TE);  // N + 20*TN

    const int* srcA = edge_index;
    const int* dstA = edge_index + E;

    detect_dtype<<<1, 64, 0, stream>>>(hs_init);
    hipMemsetAsync(agg_s, 0, (size_t)2 * ND * sizeof(float), stream);
    hipMemsetAsync(meta, 0, (size_t)(128 + 2 * N) * sizeof(int), stream);  // meta+ndeg+ecur_n
    hipMemsetAsync(elist, 0xFF, (size_t)(E + 20 * TE + N + 20 * TN) * sizeof(int), stream);
    init_state<<<N, D, 0, stream>>>(hs_init, gate, hsb, hfb, d_out, ND);

    prep_weights<<<(WT_TOTAL + 255) / 256, 256, 0, stream>>>(
        Ws1, Ws2, Wf1, Wf2, Wnf1, Wnf2, Gs_wih, Gf_wih, wt);

    int mx = (E > N) ? E : N;
    count_bins<<<(mx + 255) / 256, 256, 0, stream>>>(dstA, gate, lev, E, N, ecnt, ncnt, ndeg);
    scan_offsets<<<1, 64, 0, stream>>>(ecnt, ncnt, eoff, noff);
    fill_bins<<<(N + 255) / 256, 256, 0, stream>>>(gate, lev, N, noff, ncur, nlist);
    bucket_scan<<<20, 256, 0, stream>>>(nlist, noff, ncnt, eoff, ndeg, nodeoff);
    fill_edges<<<(E + 255) / 256, 256, 0, stream>>>(dstA, lev, E, nodeoff, ecur_n, elist);

    int gridE = (E + 20 * TE) / TE + 1;
    int gridNcap = cap / TN;
    for (int level = 1; level < NLEV; ++level) {
        edge_mfma<<<gridE, 256, 0, stream>>>(hsb, hfb, wt,
                                             bs1, bs2, bf1, bf2, bnf1, bnf2,
                                             dstA, srcA, gate, eoff, elist,
                                             agg_s, agg_f, level);
        node_fused<<<gridNcap, 768, 0, stream>>>(agg_s, agg_f, wt,
                                                 Gs_bih, Gs_bhh, Gf_bih, Gf_bhh,
                                                 hsb, hfb, d_out, ND,
                                                 gate, noff, nlist, level);
    }
}

// Round 14
// 242.122 us; speedup vs baseline: 15.3660x; 1.0598x over previous
//
#include <hip/hip_runtime.h>
#include <hip/hip_bf16.h>

typedef __hip_bfloat16 bf16;
typedef unsigned short ushortT;
typedef __attribute__((ext_vector_type(8))) short bf16x8;
typedef __attribute__((ext_vector_type(4))) float f32x4;

#define D 128
#define NLEV 5
#define TE 16  // edges per tile (MFMA M=16)
#define TN 16  // nodes per tile

// weight blob element offsets (bf16 elements), all stored transposed [C][K]
#define OFF_S1 0          // [5][128][128]
#define OFF_S2 81920      // [5][128][128]
#define OFF_F1 163840     // [4][128][256]
#define OFF_F2 294912     // [4][128][128]
#define OFF_NF1 360448    // [128][128]
#define OFF_NF2 376832    // [128][128]
#define OFF_GSH 393216    // [5][384][128] Gs_wih hi
#define OFF_GFH 638976    // [5][384][128] Gf_wih hi
#define OFF_GSL 884736    // [5][384][128] Gs_wih lo
#define OFF_GFL 1130496   // [5][384][128] Gf_wih lo
#define WT_TOTAL 1376256

// gate code -> t (enumerate index in CODES=[3,2,5,1,4]); index 0 unused
__constant__ int TMAP[6] = { -1, 3, 1, 0, 4, 2 };
// gate code -> func-aggregator index (FIDX={3:0,5:1,1:2,4:3}); codes 0,2 unused
__constant__ int FMAP[6] = { -1, 2, -1, 0, 3, 1 };

// dtype flag: 1 = float tensors stored as bf16, 0 = stored as float32
__device__ int g_flag;

__device__ __forceinline__ float sigm(float x) { return 1.0f / (1.0f + __expf(-x)); }

__device__ __forceinline__ ushortT f2b(float v) {
    bf16 h = __float2bfloat16(v);
    return *reinterpret_cast<ushortT*>(&h);
}

template <int ISB>
__device__ __forceinline__ float ld(const void* p, size_t i) {
    if (ISB) return __bfloat162float(((const bf16*)p)[i]);
    return ((const float*)p)[i];
}

__device__ __forceinline__ float ldx(int isb, const void* p, size_t i) {
    return isb ? __bfloat162float(((const bf16*)p)[i]) : ((const float*)p)[i];
}

// ===== fused setup: role-partitioned blocks =====
// roles: [0,B_init): state-init + agg-zero (2 nodes/block)
//        [B_init,B_init+B_cnt): count_bins
//        [B_init+B_cnt, ...): prep_weights
// dtype sniff computed block-locally (reads the same hot 256B of hs_init);
// block 0 publishes g_flag for the later edge/node kernels.
__global__ __launch_bounds__(256) void setup_a(
    const void* __restrict__ hs_init, const int* __restrict__ gate,
    const int* __restrict__ dstA, const int* __restrict__ lev,
    int E, int N, int ND,
    ushortT* __restrict__ hsb, ushortT* __restrict__ hfb, void* __restrict__ out,
    float* __restrict__ agg_s, float* __restrict__ agg_f,
    int* __restrict__ ecnt, int* __restrict__ ncnt, int* __restrict__ ndeg,
    const void* Ws1, const void* Ws2, const void* Wf1, const void* Wf2,
    const void* Wnf1, const void* Wnf2, const void* Gs, const void* Gf,
    ushortT* __restrict__ wt, int B_init, int B_cnt) {
    __shared__ int sfl;
    __shared__ int lc[40];
    int tid = threadIdx.x;
    int bid = blockIdx.x;

    if (tid < 64) {
        float x = __bfloat162float(((const bf16*)hs_init)[2 * tid]);
        float ax = fabsf(x);
        bool sane = (x == 0.0f) || (ax > 1e-4f && ax < 64.0f);
        unsigned long long m = __ballot(sane);
        if (tid == 0) sfl = (__popcll(m) >= 32) ? 1 : 0;
    }
    __syncthreads();
    int isb = sfl;
    if (bid == 0 && tid == 0) g_flag = isb;

    if (bid < B_init) {
        // ---- init role: 2 nodes per block ----
        int v = (bid << 1) | (tid >> 7);
        int j = tid & 127;
        if (v < N) {
            size_t idx = (size_t)v * D + j;
            bool pi = (gate[v] == 0);
            if (isb) {
                ushortT bval = pi ? ((const ushortT*)hs_init)[idx] : 0;  // exact bf16 copy
                hsb[idx] = bval; hfb[idx] = 0;
                ((ushortT*)out)[idx] = bval;
                ((ushortT*)out)[ND + idx] = 0;
            } else {
                float val = pi ? ((const float*)hs_init)[idx] : 0.f;
                hsb[idx] = f2b(val); hfb[idx] = 0;
                ((float*)out)[idx] = val;
                ((float*)out)[ND + idx] = 0.f;
            }
            agg_s[idx] = 0.f;
            agg_f[idx] = 0.f;
        }
    } else if (bid < B_init + B_cnt) {
        // ---- count role ----
        if (tid < 40) lc[tid] = 0;
        __syncthreads();
        int i = (bid - B_init) * 256 + tid;
        if (i < E) {
            int d = dstA[i]; int l = lev[d];
            if (l >= 1 && l < NLEV) {
                atomicAdd(&lc[(l - 1) * 5 + TMAP[gate[d]]], 1);
                atomicAdd(&ndeg[d], 1);
            }
        }
        if (i < N) {
            int l = lev[i];
            if (l >= 1 && l < NLEV && gate[i] >= 1)
                atomicAdd(&lc[20 + (l - 1) * 5 + TMAP[gate[i]]], 1);
        }
        __syncthreads();
        if (tid < 20 && lc[tid]) atomicAdd(&ecnt[tid], lc[tid]);
        if (tid >= 20 && tid < 40 && lc[tid]) atomicAdd(&ncnt[tid - 20], lc[tid]);
    } else {
        // ---- weight-prep role ----
        int i = (bid - B_init - B_cnt) * 256 + tid;
        if (i >= WT_TOTAL) return;
        const void* src; int Kd, C, rem, mode = 0;  // 0: plain, 1: hi, 2: lo
        if (i < OFF_S2)       { src = Ws1;  rem = i;           Kd = 128; C = 128; }
        else if (i < OFF_F1)  { src = Ws2;  rem = i - OFF_S2;  Kd = 128; C = 128; }
        else if (i < OFF_F2)  { src = Wf1;  rem = i - OFF_F1;  Kd = 256; C = 128; }
        else if (i < OFF_NF1) { src = Wf2;  rem = i - OFF_F2;  Kd = 128; C = 128; }
        else if (i < OFF_NF2) { src = Wnf1; rem = i - OFF_NF1; Kd = 128; C = 128; }
        else if (i < OFF_GSH) { src = Wnf2; rem = i - OFF_NF2; Kd = 128; C = 128; }
        else if (i < OFF_GFH) { src = Gs;   rem = i - OFF_GSH; Kd = 128; C = 384; mode = 1; }
        else if (i < OFF_GSL) { src = Gf;   rem = i - OFF_GFH; Kd = 128; C = 384; mode = 1; }
        else if (i < OFF_GFL) { src = Gs;   rem = i - OFF_GSL; Kd = 128; C = 384; mode = 2; }
        else                  { src = Gf;   rem = i - OFF_GFL; Kd = 128; C = 384; mode = 2; }
        int n = rem / (Kd * C);
        int r2 = rem % (Kd * C);
        int c = r2 / Kd;
        int k = r2 % Kd;
        size_t si = (size_t)n * Kd * C + (size_t)k * C + c;
        float v = ldx(isb, src, si);
        ushortT o;
        if (mode == 2) {
            bf16 h = __float2bfloat16(v);
            o = f2b(v - __bfloat162float(h));   // lo residue (0 when src is bf16)
        } else {
            o = f2b(v);
        }
        wt[i] = o;
    }
}

__global__ void scan_offsets(const int* __restrict__ ecnt, const int* __restrict__ ncnt,
                             int* __restrict__ eoff, int* __restrict__ noff) {
    if (threadIdx.x == 0 && blockIdx.x == 0) {
        int o = 0;
        for (int b = 0; b < 20; ++b) { eoff[b] = o; o += ((ecnt[b] + TE - 1) / TE) * TE; }
        eoff[20] = o;
        o = 0;
        for (int b = 0; b < 20; ++b) { noff[b] = o; o += ((ncnt[b] + TN - 1) / TN) * TN; }
        noff[20] = o;
    }
}

// nodes -> nlist (bucketed; padding slots left as garbage, masked by ncnt)
__global__ void fill_bins(const int* __restrict__ gate, const int* __restrict__ lev, int N,
                          const int* __restrict__ noff, int* __restrict__ ncur,
                          int* __restrict__ nlist) {
    __shared__ int nc[20], nb[20];
    int tid = threadIdx.x;
    if (tid < 20) nc[tid] = 0;
    __syncthreads();
    int i = blockIdx.x * blockDim.x + tid;
    int bn = -1, rn = 0;
    if (i < N) {
        int l = lev[i];
        if (l >= 1 && l < NLEV && gate[i] >= 1) { bn = (l - 1) * 5 + TMAP[gate[i]]; rn = atomicAdd(&nc[bn], 1); }
    }
    __syncthreads();
    if (tid < 20) nb[tid] = nc[tid] ? atomicAdd(&ncur[tid], nc[tid]) : 0;
    __syncthreads();
    if (bn >= 0) nlist[noff[bn] + nb[bn] + rn] = i;
}

// per-bucket prefix-scan of node degrees -> nodeoff[v]
__global__ __launch_bounds__(256) void bucket_scan(
    const int* __restrict__ nlist, const int* __restrict__ noff,
    const int* __restrict__ ncnt, const int* __restrict__ eoff,
    const int* __restrict__ ndeg, int* __restrict__ nodeoff) {
    int b = blockIdx.x;  // 0..19
    int start = noff[b];
    int cnt = ncnt[b];
    int ebase = eoff[b];
    __shared__ int sc[256];
    int tid = threadIdx.x;
    int carry = 0;
    for (int chunk = 0; chunk < cnt; chunk += 256) {
        __syncthreads();
        int i = chunk + tid;
        int v = -1, dg = 0;
        if (i < cnt) { v = nlist[start + i]; dg = ndeg[v]; }
        sc[tid] = dg;
        __syncthreads();
        for (int off = 1; off < 256; off <<= 1) {
            int y = (tid >= off) ? sc[tid - off] : 0;
            __syncthreads();
            sc[tid] += y;
            __syncthreads();
        }
        if (v >= 0) nodeoff[v] = ebase + carry + (sc[tid] - dg);
        carry += sc[255];
    }
}

// edges -> elist, dst-contiguous
__global__ void fill_edges(const int* __restrict__ dstA, const int* __restrict__ lev,
                           int E, const int* __restrict__ nodeoff,
                           int* __restrict__ ecur_n, int* __restrict__ elist) {
    int i = blockIdx.x * blockDim.x + threadIdx.x;
    if (i >= E) return;
    int d = dstA[i];
    int l = lev[d];
    if (l >= 1 && l < NLEV) {
        int pos = nodeoff[d] + atomicAdd(&ecur_n[d], 1);
        elist[pos] = i;
    }
}

// ================= MFMA edge pass (dst-grouped tiles; LDS pre-reduced atomics) =================
// validity is positional: tile's bucket found from eoff, valid prefix from ecnt (no sentinels)
__global__ __launch_bounds__(256) void edge_mfma(
    const ushortT* __restrict__ hsb, const ushortT* __restrict__ hfb,
    const ushortT* __restrict__ wt,
    const void* __restrict__ bs1, const void* __restrict__ bs2,
    const void* __restrict__ bf1, const void* __restrict__ bf2,
    const void* __restrict__ bnf1, const void* __restrict__ bnf2,
    const int* __restrict__ dstA, const int* __restrict__ srcA,
    const int* __restrict__ gate,
    const int* __restrict__ eoff, const int* __restrict__ ecnt,
    const int* __restrict__ elist,
    float* __restrict__ agg_s, float* __restrict__ agg_f, int level) {
    int lvl = (level - 1) * 5;
    int lo = eoff[lvl];
    int hi = eoff[lvl + 5];
    int base = lo + blockIdx.x * TE;
    if (base >= hi) return;
    int b = 0;
#pragma unroll
    for (int bb = 1; bb < 5; ++bb) if (base >= eoff[lvl + bb]) b = bb;
    int nvalid = eoff[lvl + b] + ecnt[lvl + b] - base;
    if (nvalid <= 0) return;
    if (nvalid > TE) nvalid = TE;

    __shared__ int se[TE], de[TE];
    __shared__ bf16 hid[2][16][136];      // 272B rows: 16B-aligned
    __shared__ float emsg[2][16][128];    // per-edge messages (+bias) for pre-reduction

    int tid = threadIdx.x;
    int wv = tid >> 6, pass = wv >> 1, hc = wv & 1, l = tid & 63;
    int lg = l >> 4, lr = l & 15;
    int isb = g_flag;

    int c = gate[dstA[elist[base]]];   // uniform over tile
    int t = TMAP[c], fi = FMAP[c];

    if (tid < TE) {
        if (tid < nvalid) {
            int e = elist[base + tid];
            se[tid] = srcA[e];
            de[tid] = dstA[e];
        } else {
            se[tid] = -1;
            de[tid] = -1;
        }
    }
    __syncthreads();

    int src = se[lr];   // A-operand row owned by this lane

    // ---- layer 1 ----
    int KS1; size_t wb1; int K1;
    if (pass == 0)      { KS1 = 4; wb1 = OFF_S1 + (size_t)t * 16384; K1 = 128; }
    else if (c == 2)    { KS1 = 4; wb1 = OFF_NF1; K1 = 128; }
    else                { KS1 = 8; wb1 = OFF_F1 + (size_t)fi * 32768; K1 = 256; }

    f32x4 a0 = {0.f,0.f,0.f,0.f}, a1 = a0, a2 = a0, a3 = a0;
    for (int ks = 0; ks < KS1; ++ks) {
        bf16x8 a = {0,0,0,0,0,0,0,0};
        if (src >= 0) {
            int kk = ks * 32 + lg * 8;
            const ushortT* ap;
            if (pass == 0)      ap = hsb + (size_t)src * D + kk;
            else if (c == 2)    ap = hfb + (size_t)src * D + kk;
            else                ap = (kk < 128) ? (hsb + (size_t)src * D + kk)
                                                : (hfb + (size_t)src * D + (kk - 128));
            a = *(const bf16x8*)ap;
        }
        int kb = ks * 32 + lg * 8;
        {
            bf16x8 b2 = *(const bf16x8*)&wt[wb1 + (size_t)(hc * 64 + 0 * 16 + lr) * K1 + kb];
            a0 = __builtin_amdgcn_mfma_f32_16x16x32_bf16(a, b2, a0, 0, 0, 0);
        }
        {
            bf16x8 b2 = *(const bf16x8*)&wt[wb1 + (size_t)(hc * 64 + 1 * 16 + lr) * K1 + kb];
            a1 = __builtin_amdgcn_mfma_f32_16x16x32_bf16(a, b2, a1, 0, 0, 0);
        }
        {
            bf16x8 b2 = *(const bf16x8*)&wt[wb1 + (size_t)(hc * 64 + 2 * 16 + lr) * K1 + kb];
            a2 = __builtin_amdgcn_mfma_f32_16x16x32_bf16(a, b2, a2, 0, 0, 0);
        }
        {
            bf16x8 b2 = *(const bf16x8*)&wt[wb1 + (size_t)(hc * 64 + 3 * 16 + lr) * K1 + kb];
            a3 = __builtin_amdgcn_mfma_f32_16x16x32_bf16(a, b2, a3, 0, 0, 0);
        }
    }

    // bias + relu -> bf16 hidden in LDS
    const void* b1p = (pass == 0) ? bs1 : (c == 2 ? bnf1 : bf1);
    size_t b1o = (pass == 0) ? (size_t)t * D : (c == 2 ? 0 : (size_t)fi * D);
    {
        f32x4 av[4] = { a0, a1, a2, a3 };
#pragma unroll
        for (int ct = 0; ct < 4; ++ct) {
            int cc = hc * 64 + ct * 16 + lr;
            float bb = ldx(isb, b1p, b1o + cc);
#pragma unroll
            for (int r = 0; r < 4; ++r) {
                int m = lg * 4 + r;
                float v = fmaxf(av[ct][r] + bb, 0.f);
                hid[pass][m][cc] = __float2bfloat16(v);
            }
        }
    }
    __syncthreads();

    // ---- layer 2 (K=128 over hidden) ----
    size_t wb2 = (pass == 0) ? (OFF_S2 + (size_t)t * 16384)
                             : (c == 2 ? (size_t)OFF_NF2 : (OFF_F2 + (size_t)fi * 16384));
    a0 = (f32x4){0.f,0.f,0.f,0.f}; a1 = a0; a2 = a0; a3 = a0;
#pragma unroll
    for (int ks = 0; ks < 4; ++ks) {
        bf16x8 a = *(const bf16x8*)&hid[pass][lr][ks * 32 + lg * 8];
        int kb = ks * 32 + lg * 8;
        {
            bf16x8 b2 = *(const bf16x8*)&wt[wb2 + (size_t)(hc * 64 + 0 * 16 + lr) * 128 + kb];
            a0 = __builtin_amdgcn_mfma_f32_16x16x32_bf16(a, b2, a0, 0, 0, 0);
        }
        {
            bf16x8 b2 = *(const bf16x8*)&wt[wb2 + (size_t)(hc * 64 + 1 * 16 + lr) * 128 + kb];
            a1 = __builtin_amdgcn_mfma_f32_16x16x32_bf16(a, b2, a1, 0, 0, 0);
        }
        {
            bf16x8 b2 = *(const bf16x8*)&wt[wb2 + (size_t)(hc * 64 + 2 * 16 + lr) * 128 + kb];
            a2 = __builtin_amdgcn_mfma_f32_16x16x32_bf16(a, b2, a2, 0, 0, 0);
        }
        {
            bf16x8 b2 = *(const bf16x8*)&wt[wb2 + (size_t)(hc * 64 + 3 * 16 + lr) * 128 + kb];
            a3 = __builtin_amdgcn_mfma_f32_16x16x32_bf16(a, b2, a3, 0, 0, 0);
        }
    }

    // per-edge bias folded in, stash to LDS for same-dst pre-reduction
    const void* b2p = (pass == 0) ? bs2 : (c == 2 ? bnf2 : bf2);
    size_t b2o = (pass == 0) ? (size_t)t * D : (c == 2 ? 0 : (size_t)fi * D);
    {
        f32x4 av[4] = { a0, a1, a2, a3 };
#pragma unroll
        for (int ct = 0; ct < 4; ++ct) {
            int cc = hc * 64 + ct * 16 + lr;
            float bb = ldx(isb, b2p, b2o + cc);
#pragma unroll
            for (int r = 0; r < 4; ++r) {
                int m = lg * 4 + r;
                emsg[pass][m][cc] = av[ct][r] + bb;
            }
        }
    }
    __syncthreads();

    // run-detect on de[] (dst-grouped): one atomic per distinct dst per col
    float* aggp = pass ? agg_f : agg_s;
    int col = hc * 64 + l;
    float s = 0.f;
    for (int m = 0; m < TE; ++m) {
        int d = de[m];
        if (d < 0) break;                 // padding is contiguous at tile end
        s += emsg[pass][m][col];
        bool flush = (m == TE - 1) || (de[m + 1] != d);
        if (flush) {
            atomicAdd(&aggp[(size_t)d * D + col], s);
            s = 0.f;
        }
    }
}

// ===== fused node GRU: MFMA gi (hi/lo compensated) -> LDS -> nonlinearity =====
// validity from ncnt (positional); epilogue writes FINAL output rows directly
template <int ISB>
__device__ void node_fused_body(
    const float* __restrict__ agg_s, const float* __restrict__ agg_f,
    const ushortT* __restrict__ wt,
    const void* __restrict__ Gs_bih, const void* __restrict__ Gs_bhh,
    const void* __restrict__ Gf_bih, const void* __restrict__ Gf_bhh,
    ushortT* __restrict__ hsb, ushortT* __restrict__ hfb,
    void* __restrict__ out, int ND,
    const int* __restrict__ gate,
    const int* __restrict__ noff, const int* __restrict__ ncnt,
    const int* __restrict__ nlist,
    int level, float (*gi)[3][16][128]) {
    int lvl = (level - 1) * 5;
    int lo = noff[lvl];
    int hi = noff[lvl + 5];
    int base = lo + blockIdx.x * TN;
    if (base >= hi) return;
    int b = 0;
#pragma unroll
    for (int bb = 1; bb < 5; ++bb) if (base >= noff[lvl + bb]) b = bb;
    int nvalid = noff[lvl + b] + ncnt[lvl + b] - base;
    if (nvalid <= 0) return;
    if (nvalid > TN) nvalid = TN;

    int tid = threadIdx.x;
    int w = tid >> 6, l = tid & 63;
    int lg = l >> 4, lr = l & 15;
    int p = w / 6, cg = w % 6;
    int t = TMAP[gate[nlist[base]]];

    const float* agg = p ? agg_f : agg_s;
    size_t wbh = (p ? OFF_GFH : OFF_GSH) + (size_t)t * 49152;
    size_t wbl = (p ? OFF_GFL : OFF_GSL) + (size_t)t * 49152;

    int v = (lr < nvalid) ? nlist[base + lr] : -1;   // A-operand row owned by this lane

    f32x4 acc[4];
#pragma unroll
    for (int q = 0; q < 4; ++q) acc[q] = (f32x4){0.f, 0.f, 0.f, 0.f};

    for (int ks = 0; ks < 4; ++ks) {
        bf16x8 ahi = {0,0,0,0,0,0,0,0}, alo = ahi;
        if (v >= 0) {
            const float* ap = agg + (size_t)v * D + ks * 32 + lg * 8;
            float4 f0 = *(const float4*)ap;
            float4 f1 = *(const float4*)(ap + 4);
            float av[8] = { f0.x, f0.y, f0.z, f0.w, f1.x, f1.y, f1.z, f1.w };
#pragma unroll
            for (int j = 0; j < 8; ++j) {
                bf16 h = __float2bfloat16(av[j]);
                ahi[j] = (short)*reinterpret_cast<ushortT*>(&h);
                float r = av[j] - __bfloat162float(h);
                bf16 l2 = __float2bfloat16(r);
                alo[j] = (short)*reinterpret_cast<ushortT*>(&l2);
            }
        }
        int kb = ks * 32 + lg * 8;
#pragma unroll
        for (int q = 0; q < 4; ++q) {
            int col = (cg * 4 + q) * 16 + lr;
            bf16x8 bh = *(const bf16x8*)&wt[wbh + (size_t)col * 128 + kb];
            acc[q] = __builtin_amdgcn_mfma_f32_16x16x32_bf16(ahi, bh, acc[q], 0, 0, 0);
            acc[q] = __builtin_amdgcn_mfma_f32_16x16x32_bf16(alo, bh, acc[q], 0, 0, 0);
            if (!ISB) {   // f32 weights: add hi*lo correction
                bf16x8 bl = *(const bf16x8*)&wt[wbl + (size_t)col * 128 + kb];
                acc[q] = __builtin_amdgcn_mfma_f32_16x16x32_bf16(ahi, bl, acc[q], 0, 0, 0);
            }
        }
    }

#pragma unroll
    for (int q = 0; q < 4; ++q) {
        int ct = cg * 4 + q;
        int g = ct >> 3, j = (ct & 7) * 16 + lr;
#pragma unroll
        for (int r = 0; r < 4; ++r) gi[p][g][lg * 4 + r][j] = acc[q][r];
    }
    __syncthreads();

    if (tid < 256) {
        int pp = tid >> 7, j = tid & 127;
        const void* bih = pp ? Gf_bih : Gs_bih;
        const void* bhh = pp ? Gf_bhh : Gs_bhh;
        float br = ld<ISB>(bih, (size_t)t * 384 + j);
        float bz = ld<ISB>(bih, (size_t)t * 384 + 128 + j);
        float bn = ld<ISB>(bih, (size_t)t * 384 + 256 + j);
        float hr = ld<ISB>(bhh, (size_t)t * 384 + j);
        float hz = ld<ISB>(bhh, (size_t)t * 384 + 128 + j);
        float hn = ld<ISB>(bhh, (size_t)t * 384 + 256 + j);
        ushortT* hb = pp ? hfb : hsb;
#pragma unroll
        for (int r = 0; r < TN; ++r) {
            if (r >= nvalid) break;
            int vv = nlist[base + r];
            float rr = sigm(gi[pp][0][r][j] + br + hr);
            float z = sigm(gi[pp][1][r][j] + bz + hz);
            float n = tanhf(gi[pp][2][r][j] + bn + rr * hn);
            float outv = (1.f - z) * n;
            size_t oidx = (size_t)pp * ND + (size_t)vv * D + j;
            if (ISB) ((ushortT*)out)[oidx] = f2b(outv);
            else     ((float*)out)[oidx] = outv;
            hb[(size_t)vv * D + j] = f2b(outv);
        }
    }
}

__global__ __launch_bounds__(768) void node_fused(
    const float* agg_s, const float* agg_f, const ushortT* wt,
    const void* Gs_bih, const void* Gs_bhh,
    const void* Gf_bih, const void* Gf_bhh,
    ushortT* hsb, ushortT* hfb, void* out, int ND,
    const int* gate, const int* noff, const int* ncnt, const int* nlist, int level) {
    __shared__ float gi[2][3][16][128];
    if (g_flag)
        node_fused_body<1>(agg_s, agg_f, wt, Gs_bih, Gs_bhh, Gf_bih, Gf_bhh,
                           hsb, hfb, out, ND, gate, noff, ncnt, nlist, level, gi);
    else
        node_fused_body<0>(agg_s, agg_f, wt, Gs_bih, Gs_bhh, Gf_bih, Gf_bhh,
                           hsb, hfb, out, ND, gate, noff, ncnt, nlist, level, gi);
}

extern "C" void kernel_launch(void* const* d_in, const int* in_sizes, int n_in,
                              void* d_out, int out_size, void* d_ws, size_t ws_size,
                              hipStream_t stream) {
    const void* hs_init = d_in[0];
    const void* Ws1 = d_in[1];
    const void* bs1 = d_in[2];
    const void* Ws2 = d_in[3];
    const void* bs2 = d_in[4];
    const void* Wf1 = d_in[5];
    const void* bf1 = d_in[6];
    const void* Wf2 = d_in[7];
    const void* bf2 = d_in[8];
    const void* Wnf1 = d_in[9];
    const void* bnf1 = d_in[10];
    const void* Wnf2 = d_in[11];
    const void* bnf2 = d_in[12];
    const void* Gs_wih = d_in[13];
    const void* Gs_bih = d_in[15];
    const void* Gs_bhh = d_in[16];
    const void* Gf_wih = d_in[17];
    const void* Gf_bih = d_in[19];
    const void* Gf_bhh = d_in[20];
    const int* edge_index = (const int*)d_in[21];
    const int* gate = (const int*)d_in[22];
    const int* lev = (const int*)d_in[23];

    int E = in_sizes[21] / 2;
    int N = in_sizes[22];
    int ND = N * D;
    int cap = ((N / NLEV + 5 * TN + 64) + TN - 1) / TN * TN;

    float* agg_s = (float*)d_ws;
    float* agg_f = agg_s + ND;
    ushortT* hsb = (ushortT*)(agg_f + ND);           // ND ushorts
    ushortT* hfb = hsb + ND;
    ushortT* wt = hfb + ND;                          // WT_TOTAL ushorts
    int* meta = (int*)(wt + WT_TOTAL);
    int* ecnt = meta;            // 20
    int* ncnt = ecnt + 20;       // 20
    int* ncur = ncnt + 20;       // 20
    int* eoff = ncur + 20;       // 21
    int* noff = eoff + 21;       // 21  (meta total 102; pad to 128)
    int* ndeg = meta + 128;      // N
    int* ecur_n = ndeg + N;      // N
    int* nodeoff = ecur_n + N;   // N
    int* elist = nodeoff + N;    // E + 20*TE
    int* nlist = elist + (E + 20 * TE);  // N + 20*TN

    const int* srcA = edge_index;
    const int* dstA = edge_index + E;

    // single memset: bucket counters + per-node degree/cursor arrays
    hipMemsetAsync(meta, 0, (size_t)(128 + 2 * N) * sizeof(int), stream);

    int mx = (E > N) ? E : N;
    int B_init = (N + 1) / 2;
    int B_cnt = (mx + 255) / 256;
    int B_prep = (WT_TOTAL + 255) / 256;
    setup_a<<<B_init + B_cnt + B_prep, 256, 0, stream>>>(
        hs_init, gate, dstA, lev, E, N, ND,
        hsb, hfb, d_out, agg_s, agg_f,
        ecnt, ncnt, ndeg,
        Ws1, Ws2, Wf1, Wf2, Wnf1, Wnf2, Gs_wih, Gf_wih,
        wt, B_init, B_cnt);

    scan_offsets<<<1, 64, 0, stream>>>(ecnt, ncnt, eoff, noff);
    fill_bins<<<(N + 255) / 256, 256, 0, stream>>>(gate, lev, N, noff, ncur, nlist);
    bucket_scan<<<20, 256, 0, stream>>>(nlist, noff, ncnt, eoff, ndeg, nodeoff);
    fill_edges<<<(E + 255) / 256, 256, 0, stream>>>(dstA, lev, E, nodeoff, ecur_n, elist);

    int gridE = (E + 20 * TE) / TE + 1;
    int gridNcap = cap / TN;
    for (int level = 1; level < NLEV; ++level) {
        edge_mfma<<<gridE, 256, 0, stream>>>(hsb, hfb, wt,
                                             bs1, bs2, bf1, bf2, bnf1, bnf2,
                                             dstA, srcA, gate, eoff, ecnt, elist,
                                             agg_s, agg_f, level);
        node_fused<<<gridNcap, 768, 0, stream>>>(agg_s, agg_f, wt,
                                                 Gs_bih, Gs_bhh, Gf_bih, Gf_bhh,
                                                 hsb, hfb, d_out, ND,
                                                 gate, noff, ncnt, nlist, level);
    }
}